// Round 1
// baseline (608.925 us; speedup 1.0000x reference)
//
#include <hip/hip_runtime.h>
#include <hip/hip_bf16.h>
#include <stdint.h>

typedef float f32x4 __attribute__((ext_vector_type(4)));
typedef short bf16x8 __attribute__((ext_vector_type(8)));
typedef float fragc __attribute__((ext_vector_type(4)));

__device__ __forceinline__ uint32_t pkbf16(float lo, float hi) {
  // truncating f32->bf16 pair pack: low half = lo, high half = hi
  return (__float_as_uint(hi) & 0xffff0000u) | (__float_as_uint(lo) >> 16);
}

// a: [1024 s][512 i][64 h] f32 ; b: [1024 s][512 j][64 h] f32
// out: [512 i][512 j][64 h] f32 = (1/1024) * sum_s a[s,i,h]*b[s,j,h]
// block: 512 thr (8 waves), tile 128i x 128j x 4h; grid = 4*4*16 = 256 blocks
__global__ __launch_bounds__(512) void opm_kernel(const float* __restrict__ Ag,
                                                  const float* __restrict__ Bg,
                                                  float* __restrict__ Og) {
  // LDS: A bf16 [4h][128 i][32 s] at 0 (32KB), B same at 32768. 16B-slice XOR swizzle.
  __shared__ alignas(16) unsigned char lds[65536];

  const int bid = blockIdx.x;
  // XCD-aware decode: XCD x = bid&7 gets h-groups {2x,2x+1} x all 16 (i,j)-tiles
  const int x    = bid & 7;
  const int kk   = bid >> 3;            // 0..31
  const int hg   = 2 * x + (kk >> 4);   // 0..15
  const int tile = kk & 15;
  const int i0   = (tile >> 2) * 128;
  const int j0   = (tile & 3) * 128;
  const int h0   = hg * 4;

  const int tid  = threadIdx.x;
  const int lane = tid & 63;
  const int w    = tid >> 6;
  const int wh   = w >> 1;              // h within group (0..3)
  const int wc   = w & 1;               // j half (0..1)

  // staging mapping: thread -> (row st_i, s-quad q0 and q0+4)
  const int st_i  = tid & 127;
  const int st_q0 = tid >> 7;           // 0..3

  const f32x4* A4 = (const f32x4*)Ag;
  const f32x4* B4 = (const f32x4*)Bg;
  const int aoff = (i0 + st_i) * 16 + hg;   // float4 index: s*8192 + (i)*16 + hg
  const int boff = (j0 + st_i) * 16 + hg;

  // frag-read addressing (ds_read_b128): row = tile*16 + (lane&15), slice = lane>>4
  const int frl = lane & 15;
  const int frg = lane >> 4;
  const int swz = (frg ^ (frl & 3)) * 16;             // slice XOR (row&3), row%16 == frl
  const int ra_base = wh * 8192 + frl * 64 + swz;
  const int rb_base = 32768 + wh * 8192 + (wc * 64 + frl) * 64 + swz;

  fragc acc[8][4];
#pragma unroll
  for (int m = 0; m < 8; ++m)
#pragma unroll
    for (int n = 0; n < 4; ++n)
      acc[m][n] = (fragc)0.0f;

  f32x4 ra[8], rb[8];

#define ISSUE_LOADS(S0)                                       \
  {                                                           \
    _Pragma("unroll") for (int u = 0; u < 2; ++u) {           \
      const int q = st_q0 + 4 * u;                            \
      _Pragma("unroll") for (int r = 0; r < 4; ++r) {         \
        const int s = (S0) + q * 4 + r;                       \
        ra[u * 4 + r] = A4[s * 8192 + aoff];                  \
        rb[u * 4 + r] = B4[s * 8192 + boff];                  \
      }                                                       \
    }                                                         \
  }

  ISSUE_LOADS(0)

  for (int t = 0; t < 32; ++t) {
    __syncthreads();  // previous compute done reading LDS
    // register transpose: pack (s,s+1,s+2,s+3) bf16 per h, ds_write_b64
#pragma unroll
    for (int u = 0; u < 2; ++u) {
      const int q = st_q0 + 4 * u;
      const int wb = st_i * 64 + (((q >> 1) ^ (st_i & 3)) * 16) + (q & 1) * 8;
#pragma unroll
      for (int h = 0; h < 4; ++h) {
        uint32_t a0 = pkbf16(ra[u * 4 + 0][h], ra[u * 4 + 1][h]);
        uint32_t a1 = pkbf16(ra[u * 4 + 2][h], ra[u * 4 + 3][h]);
        *(uint2*)(lds + h * 8192 + wb) = make_uint2(a0, a1);
        uint32_t b0 = pkbf16(rb[u * 4 + 0][h], rb[u * 4 + 1][h]);
        uint32_t b1 = pkbf16(rb[u * 4 + 2][h], rb[u * 4 + 3][h]);
        *(uint2*)(lds + 32768 + h * 8192 + wb) = make_uint2(b0, b1);
      }
    }
    __syncthreads();  // LDS tile t ready
    if (t < 31) ISSUE_LOADS((t + 1) * 32)  // in flight across the MFMA cluster
    // compute: 8 m-tiles x 4 n-tiles of 16x16x32
    {
      bf16x8 fb[4];
#pragma unroll
      for (int nt = 0; nt < 4; ++nt)
        fb[nt] = *(const bf16x8*)(lds + rb_base + nt * 1024);
#pragma unroll
      for (int mt = 0; mt < 8; ++mt) {
        bf16x8 fa = *(const bf16x8*)(lds + ra_base + mt * 1024);
#pragma unroll
        for (int nt = 0; nt < 4; ++nt)
          acc[mt][nt] = __builtin_amdgcn_mfma_f32_16x16x32_bf16(fa, fb[nt], acc[mt][nt], 0, 0, 0);
      }
    }
  }
#undef ISSUE_LOADS

  // epilogue: C layout col=lane&15 (j), row=(lane>>4)*4+reg (i)
  const float scale = 1.0f / 1024.0f;
  const int jg = j0 + wc * 64 + frl;
#pragma unroll
  for (int mt = 0; mt < 8; ++mt) {
#pragma unroll
    for (int r = 0; r < 4; ++r) {
      const int ig = i0 + mt * 16 + frg * 4 + r;
      float* orow = Og + ((size_t)ig * 512 + jg) * 64 + h0 + wh;
#pragma unroll
      for (int nt = 0; nt < 4; ++nt)
        orow[nt * 16 * 64] = acc[mt][nt][r] * scale;
    }
  }
}

extern "C" void kernel_launch(void* const* d_in, const int* in_sizes, int n_in,
                              void* d_out, int out_size, void* d_ws, size_t ws_size,
                              hipStream_t stream) {
  const float* a = (const float*)d_in[0];
  const float* b = (const float*)d_in[1];
  float* out = (float*)d_out;
  opm_kernel<<<256, 512, 0, stream>>>(a, b, out);
}

// Round 2
// 450.750 us; speedup vs baseline: 1.3509x; 1.3509x over previous
//
#include <hip/hip_runtime.h>
#include <stdint.h>

typedef float f32x4 __attribute__((ext_vector_type(4)));
typedef short bf16x8 __attribute__((ext_vector_type(8)));
typedef float fragc __attribute__((ext_vector_type(4)));
typedef uint32_t u32x4 __attribute__((ext_vector_type(4)));

// pack two f32 -> (bf16(lo) | bf16(hi)<<16) via one v_perm_b32 (truncating)
__device__ __forceinline__ uint32_t pk2(float lo, float hi) {
  return __builtin_amdgcn_perm(__float_as_uint(hi), __float_as_uint(lo), 0x07060302u);
}

// a: [1024 s][512 i][64 h] f32 ; b: [1024 s][512 j][64 h] f32
// out: [512 i][512 j][64 h] f32 = (1/1024) * sum_s a[s,i,h]*b[s,j,h]
// tile: 64i x 64j x 8h per block; 512 thr (8 waves, wave = 1 h); BK=32; 512 blocks
__global__ __launch_bounds__(512, 2) void opm_kernel(const float* __restrict__ Ag,
                                                     const float* __restrict__ Bg,
                                                     float* __restrict__ Og) {
  // LDS: A bf16 [8 h][4 kq][64 i][16B] at 0 (32KB), B at 32768. i-slot ^= 4*(h>>2).
  __shared__ alignas(16) unsigned char lds[65536];

  const int bid = blockIdx.x;
  // XCD swizzle: XCD x = bid&7 owns i-panel x (all tj, all hg) -> per-s L2 window ~48KB
  const int sw   = (bid & 7) * 64 + (bid >> 3);
  const int tile = sw >> 3;
  const int hg   = sw & 7;
  const int i0   = (tile >> 3) * 64;
  const int j0   = (tile & 7) * 64;
  const int h0   = hg * 8;

  const int tid  = threadIdx.x;
  const int lane = tid & 63;
  const int w    = tid >> 6;        // wave id = h within group (0..7)

  // staging map: thread -> (h-chunk hc, row si, k-octet sq)
  const int hc = tid & 1;           // which float4 (4h) of the 8h group
  const int si = (tid >> 1) & 63;   // row (i for A, j for B)
  const int sq = tid >> 7;          // k-octet 0..3 (8 consecutive s)

  const f32x4* A4 = (const f32x4*)Ag;
  const f32x4* B4 = (const f32x4*)Bg;
  const int aoff = (i0 + si) * 16 + hg * 2 + hc;  // float4 idx: s*8192 + .
  const int boff = (j0 + si) * 16 + hg * 2 + hc;

  // LDS write base (plane h = hc*4+e added per e): sq*1024 + (si ^ 4*hc)*16
  const int wrA = sq * 1024 + ((si ^ (hc << 2)) << 4);

  // frag read: lane l: k-octet = l>>4, idx = l&15; i-slot ^= 4*(h>>2)
  const int frl = lane & 15;
  const int frg = lane >> 4;
  const int rxor = (w >> 2) << 2;
  const int rdA = w * 4096 + frg * 1024;
  const int rdB = 32768 + w * 4096 + frg * 1024;

  fragc acc[4][4];
#pragma unroll
  for (int m = 0; m < 4; ++m)
#pragma unroll
    for (int n = 0; n < 4; ++n)
      acc[m][n] = (fragc)0.0f;

  f32x4 ra[8], rb[8];

#define ISSUE_LOADS(P)                                        \
  {                                                           \
    const int sb = (P) * 32 + sq * 8;                         \
    _Pragma("unroll") for (int r = 0; r < 8; ++r) {           \
      ra[r] = A4[(sb + r) * 8192 + aoff];                     \
      rb[r] = B4[(sb + r) * 8192 + boff];                     \
    }                                                         \
  }

  ISSUE_LOADS(0)

  for (int t = 0; t < 32; ++t) {
    __syncthreads();  // previous compute done reading LDS
    // pack 8 s (k-octet) per h into 16B, one ds_write_b128 per h per side
#pragma unroll
    for (int e = 0; e < 4; ++e) {
      const int h = (hc << 2) + e;
      u32x4 pa, pb;
      pa[0] = pk2(ra[0][e], ra[1][e]); pa[1] = pk2(ra[2][e], ra[3][e]);
      pa[2] = pk2(ra[4][e], ra[5][e]); pa[3] = pk2(ra[6][e], ra[7][e]);
      pb[0] = pk2(rb[0][e], rb[1][e]); pb[1] = pk2(rb[2][e], rb[3][e]);
      pb[2] = pk2(rb[4][e], rb[5][e]); pb[3] = pk2(rb[6][e], rb[7][e]);
      *(u32x4*)(lds + h * 4096 + wrA) = pa;
      *(u32x4*)(lds + 32768 + h * 4096 + wrA) = pb;
    }
    __syncthreads();  // LDS tile t ready
    if (t < 31) ISSUE_LOADS(t + 1)  // in flight across the MFMA cluster
    {
      bf16x8 fb[4];
#pragma unroll
      for (int nt = 0; nt < 4; ++nt)
        fb[nt] = *(const bf16x8*)(lds + rdB + ((((nt * 16) + frl) ^ rxor) << 4));
#pragma unroll
      for (int mt = 0; mt < 4; ++mt) {
        bf16x8 fa = *(const bf16x8*)(lds + rdA + ((((mt * 16) + frl) ^ rxor) << 4));
#pragma unroll
        for (int nt = 0; nt < 4; ++nt)
          acc[mt][nt] = __builtin_amdgcn_mfma_f32_16x16x32_bf16(fa, fb[nt], acc[mt][nt], 0, 0, 0);
      }
    }
  }
#undef ISSUE_LOADS

  // epilogue: C layout col(j)=lane&15, row(i)=(lane>>4)*4+reg; h = h0 + wave
  const float scale = 1.0f / 1024.0f;
#pragma unroll
  for (int mt = 0; mt < 4; ++mt) {
#pragma unroll
    for (int r = 0; r < 4; ++r) {
      const int ig = i0 + mt * 16 + frg * 4 + r;
#pragma unroll
      for (int nt = 0; nt < 4; ++nt) {
        const int jg = j0 + nt * 16 + frl;
        Og[((size_t)ig * 512 + jg) * 64 + h0 + w] = acc[mt][nt][r] * scale;
      }
    }
  }
}

extern "C" void kernel_launch(void* const* d_in, const int* in_sizes, int n_in,
                              void* d_out, int out_size, void* d_ws, size_t ws_size,
                              hipStream_t stream) {
  const float* a = (const float*)d_in[0];
  const float* b = (const float*)d_in[1];
  float* out = (float*)d_out;
  opm_kernel<<<512, 512, 0, stream>>>(a, b, out);
}

// Round 3
// 224.905 us; speedup vs baseline: 2.7075x; 2.0042x over previous
//
#include <hip/hip_runtime.h>
#include <stdint.h>

typedef float f32x4 __attribute__((ext_vector_type(4)));
typedef short bf16x8 __attribute__((ext_vector_type(8)));
typedef float fragc __attribute__((ext_vector_type(4)));
typedef uint32_t u32x4 __attribute__((ext_vector_type(4)));

__device__ __forceinline__ uint32_t pk2(float lo, float hi) {
  // (bf16(lo) | bf16(hi)<<16) via one v_perm_b32 (truncating)
  return __builtin_amdgcn_perm(__float_as_uint(hi), __float_as_uint(lo), 0x07060302u);
}

__device__ __forceinline__ void gload16(const void* g, void* l) {
  __builtin_amdgcn_global_load_lds((const __attribute__((address_space(1))) uint32_t*)g,
                                   (__attribute__((address_space(3))) uint32_t*)l, 16, 0, 0);
}

#define WS_B_OFF 67108864ull  // B'' at ws + 64 MiB; total ws use = 128 MiB

// ---------- Pass 1: [1024 s][512 r][64 h] f32  ->  bf16 [64 h][128 kq][512 r][16B octet]
// byte(h,s,r) = side + ((h*128 + s/8)*512 + r)*16 + (s&7)*2
// block = (side, kq 128, hqg 4, ip 4) = 4096 blocks x 512 thr; thread = (hc 4, il 128)
// reads: wave-instr = 16 rows x 64B, all lines fully used; writes: 4 x 256B segments.
__global__ __launch_bounds__(512) void pack_kernel(const float* __restrict__ Ag,
                                                   const float* __restrict__ Bg,
                                                   uint8_t* __restrict__ ws) {
  const int bid  = blockIdx.x;
  const int side = bid & 1;
  const int kq   = (bid >> 1) & 127;
  const int hqg  = (bid >> 8) & 3;
  const int ip   = bid >> 10;

  const int t  = threadIdx.x;
  const int hc = t & 3;
  const int il = t >> 2;            // 0..127
  const int i0 = ip * 128;
  const int q  = hqg * 4 + hc;      // h-quad 0..15

  const f32x4* S4 = (const f32x4*)(side ? Bg : Ag);
  uint8_t* dstbase = ws + (side ? WS_B_OFF : 0ull);

  const int fbase = (i0 + il) * 16 + hqg * 4 + hc;  // float4 index within one s-slab
  f32x4 r[8];
#pragma unroll
  for (int e = 0; e < 8; ++e)
    r[e] = S4[(size_t)(kq * 8 + e) * 8192 + fbase];

#pragma unroll
  for (int e = 0; e < 4; ++e) {
    const int h = q * 4 + e;
    u32x4 o;
    o[0] = pk2(r[0][e], r[1][e]);
    o[1] = pk2(r[2][e], r[3][e]);
    o[2] = pk2(r[4][e], r[5][e]);
    o[3] = pk2(r[6][e], r[7][e]);
    *(u32x4*)(dstbase + ((size_t)(h * 128 + kq) * 512 + i0 + il) * 16) = o;
  }
}

// ---------- Pass 2: per-h GEMM  C_h[i,j] = (1/1024) sum_s A''[h,s,i] * B''[h,s,j]
// 128x128 tile, BK=32, 256 thr (4 waves, wave = 64x64 quadrant), double-buffered LDS,
// global_load_lds width 16 (linear LDS image [ko 4][128 r][16B], conflict-free frag reads).
// grid 1024 = 16 tiles x 64 h; XCD x owns tiles {2x,2x+1} x all h (C-line merge in L2).
__global__ __launch_bounds__(256) void gemm_kernel(const uint8_t* __restrict__ ws,
                                                   float* __restrict__ Og) {
  __shared__ alignas(16) uint8_t lds[32768];  // 2 x (A 8KB + B 8KB)

  const int bid  = blockIdx.x;
  const int x    = bid & 7;
  const int rr   = bid >> 3;            // 0..127
  const int tile = 2 * x + (rr >> 6);   // 0..15
  const int h    = rr & 63;
  const int i0   = (tile >> 2) * 128;
  const int j0   = (tile & 3) * 128;

  const uint8_t* Ab = ws + (size_t)h * 1048576;
  const uint8_t* Bb = ws + WS_B_OFF + (size_t)h * 1048576;

  const int tid = threadIdx.x;
  const int l   = tid & 63;
  const int w   = tid >> 6;             // wave 0..3
  const int mi2 = w & 1, nj2 = w >> 1;  // output quadrant
  const int frl = l & 15, frg = l >> 4; // frag row / k-octet

  fragc acc[4][4];
#pragma unroll
  for (int m = 0; m < 4; ++m)
#pragma unroll
    for (int n = 0; n < 4; ++n)
      acc[m][n] = (fragc)0.0f;

  // per k-step: each wave stages its ko = w plane (2 half-chunks of 1KB) for A and B
#define ISSUE(kt, b)                                                           \
  {                                                                            \
    _Pragma("unroll") for (int p = 0; p < 2; ++p) {                            \
      gload16(Ab + (size_t)((kt) * 4 + w) * 8192 + (i0 + p * 64 + l) * 16,     \
              lds + (b) * 16384 + w * 2048 + p * 1024);                        \
      gload16(Bb + (size_t)((kt) * 4 + w) * 8192 + (j0 + p * 64 + l) * 16,     \
              lds + (b) * 16384 + 8192 + w * 2048 + p * 1024);                 \
    }                                                                          \
  }

  ISSUE(0, 0)

  for (int kt = 0; kt < 32; ++kt) {
    __syncthreads();  // drains gload of tile kt (issued one iter ago); joins readers of buf b^1
    const int b = kt & 1;
    if (kt < 31) ISSUE(kt + 1, b ^ 1)  // overlaps with MFMA below; drained at next barrier
    const uint8_t* La = lds + b * 16384;
    const uint8_t* Lb = La + 8192;
    bf16x8 fb[4];
#pragma unroll
    for (int nt = 0; nt < 4; ++nt)
      fb[nt] = *(const bf16x8*)(Lb + frg * 2048 + (nj2 * 64 + nt * 16 + frl) * 16);
#pragma unroll
    for (int mt = 0; mt < 4; ++mt) {
      bf16x8 fa = *(const bf16x8*)(La + frg * 2048 + (mi2 * 64 + mt * 16 + frl) * 16);
#pragma unroll
      for (int nt = 0; nt < 4; ++nt)
        acc[mt][nt] = __builtin_amdgcn_mfma_f32_16x16x32_bf16(fa, fb[nt], acc[mt][nt], 0, 0, 0);
    }
  }
#undef ISSUE

  // epilogue: C col(j)=lane&15, row(i)=(lane>>4)*4+reg; out[i][j][h] (4B scatter, h-siblings
  // of each 64B line are on this XCD -> L2 merge)
  const float scale = 1.0f / 1024.0f;
#pragma unroll
  for (int mt = 0; mt < 4; ++mt) {
#pragma unroll
    for (int r = 0; r < 4; ++r) {
      const int ig = i0 + mi2 * 64 + mt * 16 + frg * 4 + r;
#pragma unroll
      for (int nt = 0; nt < 4; ++nt) {
        const int jg = j0 + nj2 * 64 + nt * 16 + frl;
        Og[((size_t)ig * 512 + jg) * 64 + h] = acc[mt][nt][r] * scale;
      }
    }
  }
}

extern "C" void kernel_launch(void* const* d_in, const int* in_sizes, int n_in,
                              void* d_out, int out_size, void* d_ws, size_t ws_size,
                              hipStream_t stream) {
  const float* a = (const float*)d_in[0];
  const float* b = (const float*)d_in[1];
  float* out = (float*)d_out;
  uint8_t* ws = (uint8_t*)d_ws;
  pack_kernel<<<4096, 512, 0, stream>>>(a, b, ws);
  gemm_kernel<<<1024, 256, 0, stream>>>(ws, out);
}

// Round 4
// 186.299 us; speedup vs baseline: 3.2685x; 1.2072x over previous
//
#include <hip/hip_runtime.h>
#include <stdint.h>

typedef float f32x4 __attribute__((ext_vector_type(4)));
typedef short bf16x8 __attribute__((ext_vector_type(8)));
typedef float fragc __attribute__((ext_vector_type(4)));
typedef uint32_t u32x4 __attribute__((ext_vector_type(4)));

__device__ __forceinline__ uint32_t pk2(float lo, float hi) {
  // (bf16(lo) | bf16(hi)<<16) via one v_perm_b32 (truncating)
  return __builtin_amdgcn_perm(__float_as_uint(hi), __float_as_uint(lo), 0x07060302u);
}

__device__ __forceinline__ void gload16(const void* g, void* l) {
  __builtin_amdgcn_global_load_lds((const __attribute__((address_space(1))) uint32_t*)g,
                                   (__attribute__((address_space(3))) uint32_t*)l, 16, 0, 0);
}

#define WS_B_OFF 67108864ull  // B'' at ws + 64 MiB

// ---------- Pass 1: [1024 s][512 r][64 h] f32 -> bf16 [64 h][128 kq][512 r][16B octet]
// LDS-bounce so BOTH global sides are coalesced:
//   reads: hc-fastest lanes -> 16 full 64B lines / instr
//   stores: il-fastest lanes -> 1KB contiguous / instr
// block = (side, kqg 32, hqg 4, ip 4) = 1024 blocks x 512 thr; 4 kq per block.
__global__ __launch_bounds__(512) void pack_kernel(const float* __restrict__ Ag,
                                                   const float* __restrict__ Bg,
                                                   uint8_t* __restrict__ ws) {
  __shared__ alignas(16) uint8_t lds[65536];  // 2 x 32KB: [16 plane][128 slot][16B]
  const int bid  = blockIdx.x;
  const int side = bid & 1;
  const int kqg  = (bid >> 1) & 31;
  const int hqg  = (bid >> 6) & 3;
  const int ip   = bid >> 8;
  const int t   = threadIdx.x;
  const int hc  = t & 3;          // write side: h-quad within group
  const int ilw = t >> 2;         // write side: row 0..127
  const int il2 = t & 127;        // read side: row (lane-fastest -> coalesced store)
  const int hs  = t >> 7;         // read side: plane quad 0..3
  const int i0  = ip * 128;

  const f32x4* S4 = (const f32x4*)(side ? Bg : Ag);
  uint8_t* dst = ws + (side ? WS_B_OFF : 0ull);
  const int fbase = (i0 + ilw) * 16 + hqg * 4 + hc;
  const int wslot = (ilw + 2 * hc) & 127;   // bank rotation (write)
  const int rslot0 = (il2 + 2 * hs) & 127;  // matching rotation (read)

  f32x4 rg[2][8];
#pragma unroll
  for (int e = 0; e < 8; ++e)
    rg[0][e] = S4[(size_t)(kqg * 32 + e) * 8192 + fbase];

#pragma unroll
  for (int it = 0; it < 4; ++it) {
    const int kq  = kqg * 4 + it;
    const int cur = it & 1;
    uint8_t* buf = lds + cur * 32768;
    // pack current regs -> LDS planes (hc*4+e)
#pragma unroll
    for (int e = 0; e < 4; ++e) {
      u32x4 o;
      o[0] = pk2(rg[cur][0][e], rg[cur][1][e]);
      o[1] = pk2(rg[cur][2][e], rg[cur][3][e]);
      o[2] = pk2(rg[cur][4][e], rg[cur][5][e]);
      o[3] = pk2(rg[cur][6][e], rg[cur][7][e]);
      *(u32x4*)(buf + (hc * 4 + e) * 2048 + wslot * 16) = o;
    }
    __syncthreads();
    if (it < 3) {  // prefetch next kq while we drain LDS
#pragma unroll
      for (int e = 0; e < 8; ++e)
        rg[cur ^ 1][e] = S4[(size_t)((kq + 1) * 8 + e) * 8192 + fbase];
    }
    // coalesced store: wave = 64 consecutive rows of one plane
#pragma unroll
    for (int e2 = 0; e2 < 4; ++e2) {
      const int p = hs * 4 + e2;
      const u32x4 o = *(const u32x4*)(buf + p * 2048 + rslot0 * 16);
      const int h = hqg * 16 + p;
      *(u32x4*)(dst + ((size_t)(h * 128 + kq) * 512 + i0 + il2) * 16) = o;
    }
  }
}

// ---------- Pass 2: C[i,j,h] = (1/1024) sum_s A''[h,s,i]*B''[h,s,j]
// tile 128i x 128j x 4h, 512 thr (8 waves: wave = (h 0..3, i-half)), BK=32, dbuf LDS 128KB.
// grid 256 = 16 tiles x 16 hg; XCD x owns a 2x2 tile quad x 8 hg (A,B both 2x L2-shared).
__global__ __launch_bounds__(512, 2) void gemm_kernel(const uint8_t* __restrict__ ws,
                                                      float* __restrict__ Og) {
  __shared__ alignas(16) uint8_t lds[131072];  // 2 x (A 32KB + B 32KB)

  const int bid = blockIdx.x;
  const int x   = bid & 7;
  const int r   = bid >> 3;  // 0..31
  const int tq  = x & 3;     // tile quad: i-pair = tq>>1, j-pair = tq&1
  const int i0  = (((tq >> 1) * 2) + (r & 1)) * 128;
  const int j0  = (((tq & 1) * 2) + ((r >> 1) & 1)) * 128;
  const int hg  = (x >> 2) * 8 + (r >> 2);  // 0..15

  const int t = threadIdx.x, lane = t & 63, w = t >> 6;
  const int hl = w & 3, half = w >> 2;
  const int frl = lane & 15, frg = lane >> 4;

  const uint8_t* Apk = ws + (size_t)(hg * 4 + hl) * 1048576ull;
  const uint8_t* Bpk = ws + WS_B_OFF + (size_t)(hg * 4 + hl) * 1048576ull;

  fragc acc[4][8];
#pragma unroll
  for (int m = 0; m < 4; ++m)
#pragma unroll
    for (int n = 0; n < 8; ++n)
      acc[m][n] = (fragc)0.0f;

  // staging: wave (hl, half) loads its h's ko-planes {2*half, 2*half+1}, A and B
#define ISSUE(kt, b)                                                              \
  {                                                                               \
    _Pragma("unroll") for (int k2 = 0; k2 < 2; ++k2) {                            \
      const int ko = half * 2 + k2;                                               \
      _Pragma("unroll") for (int p = 0; p < 2; ++p) {                             \
        gload16(Apk + (size_t)((kt) * 4 + ko) * 8192 + (i0 + p * 64 + lane) * 16, \
                lds + (b) * 65536 + hl * 8192 + ko * 2048 + p * 1024);            \
        gload16(Bpk + (size_t)((kt) * 4 + ko) * 8192 + (j0 + p * 64 + lane) * 16, \
                lds + (b) * 65536 + 32768 + hl * 8192 + ko * 2048 + p * 1024);    \
      }                                                                           \
    }                                                                             \
  }

  ISSUE(0, 0)

  for (int kt = 0; kt < 32; ++kt) {
    __syncthreads();  // drains gloads of tile kt; joins readers of buf b^1
    const int b = kt & 1;
    if (kt < 31) ISSUE(kt + 1, b ^ 1)
    const uint8_t* La = lds + b * 65536 + hl * 8192;
    const uint8_t* Lb = La + 32768;
    bf16x8 fb[8];
#pragma unroll
    for (int n = 0; n < 8; ++n)
      fb[n] = *(const bf16x8*)(Lb + frg * 2048 + (n * 16 + frl) * 16);
#pragma unroll
    for (int m = 0; m < 4; ++m) {
      bf16x8 fa = *(const bf16x8*)(La + frg * 2048 + (half * 64 + m * 16 + frl) * 16);
#pragma unroll
      for (int n = 0; n < 8; ++n)
        acc[m][n] = __builtin_amdgcn_mfma_f32_16x16x32_bf16(fa, fb[n], acc[m][n], 0, 0, 0);
    }
  }
#undef ISSUE

  // epilogue: bounce C through LDS so global stores are 16B/lane (4h contiguous).
  // chunk = 32 i-rows: LDS image [32 i][128 j][4 h] f32 = 64KB, addr-XOR swizzled.
  const float scale = 1.0f / 1024.0f;
  const int i_r = t >> 4, jo = t & 15;
#pragma unroll
  for (int cb = 0; cb < 4; ++cb) {
    __syncthreads();  // chunk cb-1 readers done / K-loop readers done
    if (half == (cb >> 1)) {
#pragma unroll
      for (int m2 = 0; m2 < 2; ++m2) {
        const int m = (cb & 1) * 2 + m2;
#pragma unroll
        for (int n = 0; n < 8; ++n) {
#pragma unroll
          for (int q = 0; q < 4; ++q) {
            const int il = m2 * 16 + frg * 4 + q;   // 0..31
            const int j  = n * 16 + frl;
            int byte = (il * 128 + j) * 16 + hl * 4;
            byte ^= ((byte >> 7) & 7) << 4;
            *(float*)(lds + byte) = acc[m][n][q] * scale;
          }
        }
      }
    }
    __syncthreads();  // chunk image ready
#pragma unroll
    for (int c = 0; c < 8; ++c) {
      int byte = (i_r * 128 + jo * 8 + c) * 16;
      byte ^= ((byte >> 7) & 7) << 4;
      const f32x4 v = *(const f32x4*)(lds + byte);
      *(f32x4*)(Og + ((size_t)(i0 + cb * 32 + i_r) * 512 + (j0 + jo * 8 + c)) * 64 + hg * 4) = v;
    }
  }
}

extern "C" void kernel_launch(void* const* d_in, const int* in_sizes, int n_in,
                              void* d_out, int out_size, void* d_ws, size_t ws_size,
                              hipStream_t stream) {
  const float* a = (const float*)d_in[0];
  const float* b = (const float*)d_in[1];
  float* out = (float*)d_out;
  uint8_t* ws = (uint8_t*)d_ws;
  pack_kernel<<<1024, 512, 0, stream>>>(a, b, ws);
  gemm_kernel<<<256, 512, 0, stream>>>(ws, out);
}

// Round 5
// 162.835 us; speedup vs baseline: 3.7395x; 1.1441x over previous
//
#include <hip/hip_runtime.h>
#include <stdint.h>

typedef float f32x4 __attribute__((ext_vector_type(4)));
typedef short bf16x8 __attribute__((ext_vector_type(8)));
typedef float fragc __attribute__((ext_vector_type(4)));
typedef uint32_t u32x4 __attribute__((ext_vector_type(4)));

__device__ __forceinline__ uint32_t pk2(float lo, float hi) {
  // (bf16(lo) | bf16(hi)<<16) via one v_perm_b32 (truncating)
  return __builtin_amdgcn_perm(__float_as_uint(hi), __float_as_uint(lo), 0x07060302u);
}

__device__ __forceinline__ void gload16(const void* g, void* l) {
  __builtin_amdgcn_global_load_lds((const __attribute__((address_space(1))) uint32_t*)g,
                                   (__attribute__((address_space(3))) uint32_t*)l, 16, 0, 0);
}

#define WS_B_OFF 67108864ull  // B'' at ws + 64 MiB

// ---------- Pass 1: [1024 s][512 r][64 h] f32 -> bf16 [64 h][128 kq][512 r][16B octet]
// Block = (side, kq s-octet, rw 32-row window) covering ALL 64 h -> every global read
// is 512 thr x 16B = 8KB fully contiguous (100% DRAM row utilization).
// Thread t holds 8 s of h-quad (t&15) at row (t>>4) -> k-octets fall out in registers.
// LDS bounce [64 h][32 r][16B], plane stride 528B (bank-quad=(h+r)%8, uniform both sides),
// then h-contiguous stores: 512B contiguous per 32-lane group.
__global__ __launch_bounds__(512) void pack_kernel(const float* __restrict__ Ag,
                                                   const float* __restrict__ Bg,
                                                   uint8_t* __restrict__ ws) {
  __shared__ alignas(16) uint8_t lds[64 * 528];  // 33792 B

  const int bid  = blockIdx.x;
  const int rw   = bid & 15;
  const int kq   = (bid >> 4) & 127;
  const int side = bid >> 11;

  const int t = threadIdx.x;

  const f32x4* S4 = (const f32x4*)(side ? Bg : Ag);
  uint8_t* dst = ws + (side ? WS_B_OFF : 0ull);

  // fully-coalesced loads: 8KB per instruction
  f32x4 rg[8];
#pragma unroll
  for (int e = 0; e < 8; ++e)
    rg[e] = S4[(size_t)(kq * 8 + e) * 8192 + rw * 512 + t];

  // pack k-octets: thread owns h-quad c = t&15, row r = t>>4
  const int c = t & 15;
  const int r = t >> 4;
#pragma unroll
  for (int hh = 0; hh < 4; ++hh) {
    const int h = c * 4 + hh;
    u32x4 o;
    o[0] = pk2(rg[0][hh], rg[1][hh]);
    o[1] = pk2(rg[2][hh], rg[3][hh]);
    o[2] = pk2(rg[4][hh], rg[5][hh]);
    o[3] = pk2(rg[6][hh], rg[7][hh]);
    *(u32x4*)(lds + h * 528 + r * 16) = o;
  }
  __syncthreads();

  // read back h-contiguous, store 512B-contiguous chunks
  const int rr = t & 31;
  const int hb = t >> 5;  // 0..15
  const int R0 = rw * 32;
#pragma unroll
  for (int e2 = 0; e2 < 4; ++e2) {
    const int h = hb * 4 + e2;
    const u32x4 v = *(const u32x4*)(lds + h * 528 + rr * 16);
    *(u32x4*)(dst + ((size_t)(h * 128 + kq) * 512 + R0 + rr) * 16) = v;
  }
}

// ---------- Pass 2: C[i,j,h] = (1/1024) sum_s A''[h,s,i]*B''[h,s,j]
// tile 128i x 128j x 4h, 512 thr (8 waves: wave = (h 0..3, i-half)), BK=32, dbuf LDS 128KB.
// grid 256 = 16 tiles x 16 hg; XCD x owns a 2x2 tile quad x 8 hg (A,B both 2x L2-shared).
__global__ __launch_bounds__(512, 2) void gemm_kernel(const uint8_t* __restrict__ ws,
                                                      float* __restrict__ Og) {
  __shared__ alignas(16) uint8_t lds[131072];  // 2 x (A 32KB + B 32KB)

  const int bid = blockIdx.x;
  const int x   = bid & 7;
  const int r   = bid >> 3;  // 0..31
  const int tq  = x & 3;     // tile quad: i-pair = tq>>1, j-pair = tq&1
  const int i0  = (((tq >> 1) * 2) + (r & 1)) * 128;
  const int j0  = (((tq & 1) * 2) + ((r >> 1) & 1)) * 128;
  const int hg  = (x >> 2) * 8 + (r >> 2);  // 0..15

  const int t = threadIdx.x, lane = t & 63, w = t >> 6;
  const int hl = w & 3, half = w >> 2;
  const int frl = lane & 15, frg = lane >> 4;

  const uint8_t* Apk = ws + (size_t)(hg * 4 + hl) * 1048576ull;
  const uint8_t* Bpk = ws + WS_B_OFF + (size_t)(hg * 4 + hl) * 1048576ull;

  fragc acc[4][8];
#pragma unroll
  for (int m = 0; m < 4; ++m)
#pragma unroll
    for (int n = 0; n < 8; ++n)
      acc[m][n] = (fragc)0.0f;

  // staging: wave (hl, half) loads its h's ko-planes {2*half, 2*half+1}, A and B
#define ISSUE(kt, b)                                                              \
  {                                                                               \
    _Pragma("unroll") for (int k2 = 0; k2 < 2; ++k2) {                            \
      const int ko = half * 2 + k2;                                               \
      _Pragma("unroll") for (int p = 0; p < 2; ++p) {                             \
        gload16(Apk + (size_t)((kt) * 4 + ko) * 8192 + (i0 + p * 64 + lane) * 16, \
                lds + (b) * 65536 + hl * 8192 + ko * 2048 + p * 1024);            \
        gload16(Bpk + (size_t)((kt) * 4 + ko) * 8192 + (j0 + p * 64 + lane) * 16, \
                lds + (b) * 65536 + 32768 + hl * 8192 + ko * 2048 + p * 1024);    \
      }                                                                           \
    }                                                                             \
  }

  ISSUE(0, 0)

  for (int kt = 0; kt < 32; ++kt) {
    __syncthreads();  // drains gloads of tile kt; joins readers of buf b^1
    const int b = kt & 1;
    if (kt < 31) ISSUE(kt + 1, b ^ 1)
    const uint8_t* La = lds + b * 65536 + hl * 8192;
    const uint8_t* Lb = La + 32768;
    bf16x8 fb[8];
#pragma unroll
    for (int n = 0; n < 8; ++n)
      fb[n] = *(const bf16x8*)(Lb + frg * 2048 + (n * 16 + frl) * 16);
#pragma unroll
    for (int m = 0; m < 4; ++m) {
      bf16x8 fa = *(const bf16x8*)(La + frg * 2048 + (half * 64 + m * 16 + frl) * 16);
#pragma unroll
      for (int n = 0; n < 8; ++n)
        acc[m][n] = __builtin_amdgcn_mfma_f32_16x16x32_bf16(fa, fb[n], acc[m][n], 0, 0, 0);
    }
  }
#undef ISSUE

  // epilogue: bounce C through LDS so global stores are 16B/lane (4h contiguous).
  // chunk = 32 i-rows: LDS image [32 i][128 j][4 h] f32 = 64KB, addr-XOR swizzled.
  const float scale = 1.0f / 1024.0f;
  const int i_r = t >> 4, jo = t & 15;
#pragma unroll
  for (int cb = 0; cb < 4; ++cb) {
    __syncthreads();  // chunk cb-1 readers done / K-loop readers done
    if (half == (cb >> 1)) {
#pragma unroll
      for (int m2 = 0; m2 < 2; ++m2) {
        const int m = (cb & 1) * 2 + m2;
#pragma unroll
        for (int n = 0; n < 8; ++n) {
#pragma unroll
          for (int q = 0; q < 4; ++q) {
            const int il = m2 * 16 + frg * 4 + q;   // 0..31
            const int j  = n * 16 + frl;
            int byte = (il * 128 + j) * 16 + hl * 4;
            byte ^= ((byte >> 7) & 7) << 4;
            *(float*)(lds + byte) = acc[m][n][q] * scale;
          }
        }
      }
    }
    __syncthreads();  // chunk image ready
#pragma unroll
    for (int c = 0; c < 8; ++c) {
      int byte = (i_r * 128 + jo * 8 + c) * 16;
      byte ^= ((byte >> 7) & 7) << 4;
      const f32x4 v = *(const f32x4*)(lds + byte);
      *(f32x4*)(Og + ((size_t)(i0 + cb * 32 + i_r) * 512 + (j0 + jo * 8 + c)) * 64 + hg * 4) = v;
    }
  }
}

extern "C" void kernel_launch(void* const* d_in, const int* in_sizes, int n_in,
                              void* d_out, int out_size, void* d_ws, size_t ws_size,
                              hipStream_t stream) {
  const float* a = (const float*)d_in[0];
  const float* b = (const float*)d_in[1];
  float* out = (float*)d_out;
  uint8_t* ws = (uint8_t*)d_ws;
  pack_kernel<<<4096, 512, 0, stream>>>(a, b, ws);
  gemm_kernel<<<256, 512, 0, stream>>>(ws, out);
}